// Round 1
// baseline (460.975 us; speedup 1.0000x reference)
//
#include <hip/hip_runtime.h>
#include <hip/hip_bf16.h>

typedef __hip_bfloat16 bf16;
typedef unsigned int u32;
typedef float f4v __attribute__((ext_vector_type(4)));

#define NN 50000
#define NE 800000
#define INC 16
#define HD 64
#define EPSV 1e-5f
#define NB1 196   // ceil(NN/256)

__device__ __forceinline__ float b2f(bf16 v) { return __bfloat162float(v); }
__device__ __forceinline__ bool is_bf(const void* det) {
  return *(const u32*)det == 0x3F803F80u;  // enc_ln_g all-ones: bf16 pair vs fp32 1.0
}

__device__ __forceinline__ float4 ldnt4(const float4* p) {
  f4v t = __builtin_nontemporal_load(reinterpret_cast<const f4v*>(p));
  float4 r; r.x = t[0]; r.y = t[1]; r.z = t[2]; r.w = t[3];
  return r;
}

template<typename T> __device__ __forceinline__ float ldv(const T* p, int i);
template<> __device__ __forceinline__ float ldv<float>(const float* p, int i) { return p[i]; }
template<> __device__ __forceinline__ float ldv<bf16>(const bf16* p, int i) { return b2f(p[i]); }

// ---- fp32 weight scratch (wf) layout, element offsets ----
#define W1F   0        // mlp_w1  [3][67][32] = 6432
#define B1F   6432     // mlp_b1  [3][32]     = 96
#define W2F   6528     // mlp_w2  [3][32][64] = 6144
#define B2F   12672    // mlp_b2  [3][64]     = 192
#define DW1F  12864    // depth_w1 [64][32]   = 2048
#define DB1F  14912    // depth_b1 [32]
#define DW2F  14944    // depth_w2 [32]
#define DB2F  14976    // depth_b2 [1]
#define VW1F  14977    // vel_w1  [64][32]    = 2048
#define VB1F  17025    // vel_b1  [32]
#define VW2F  17057    // vel_w2  [32][2]     = 64
#define VB2F  17121    // vel_b2  [2]
#define WFTOT 17123

// ---- workspace layout (float element offsets) ----
#define H_OFF    0                      // [NN*64]
#define P0_OFF   3200000                // [NN*32]
#define CSR_OFF  4800000                // [NE*4] (a0,a1,a2,src)
#define WF_OFF   8000000                // [WFTOT]
#define CNTI_OFF (WF_OFF + WFTOT)       // int [NN]
#define RS_OFF   (CNTI_OFF + NN)        // int [NN]
#define CUR_OFF  (RS_OFF + NN)          // int [NN]
#define BSUM_OFF (CUR_OFF + NN)         // int [256]
#define BOFF_OFF (BSUM_OFF + 256)       // int [256]
#define P1_OFF   (BOFF_OFF + 256)       // [NN*32] optional ping-pong buffer
#define WS_NEED_ROOMY ((size_t)(P1_OFF + NN * 32) * 4)

template<typename T>
__device__ __forceinline__ void prep_body(
    const T* w1, const T* b1, const T* w2, const T* b2,
    const T* dw1, const T* db1, const T* dw2, const T* db2,
    const T* vw1, const T* vb1, const T* vw2, const T* vb2,
    float* wf, int i) {
  float v;
  if      (i < B1F)  v = ldv(w1,  i - W1F);
  else if (i < W2F)  v = ldv(b1,  i - B1F);
  else if (i < B2F)  v = ldv(w2,  i - W2F);
  else if (i < DW1F) v = ldv(b2,  i - B2F);
  else if (i < DB1F) v = ldv(dw1, i - DW1F);
  else if (i < DW2F) v = ldv(db1, i - DB1F);
  else if (i < DB2F) v = ldv(dw2, i - DW2F);
  else if (i < VW1F) v = ldv(db2, i - DB2F);
  else if (i < VB1F) v = ldv(vw1, i - VW1F);
  else if (i < VW2F) v = ldv(vb1, i - VB1F);
  else if (i < VB2F) v = ldv(vw2, i - VW2F);
  else               v = ldv(vb2, i - VB2F);
  wf[i] = v;
}

__global__ __launch_bounds__(256) void prep_kernel(
    const void* w1, const void* b1, const void* w2, const void* b2,
    const void* dw1, const void* db1, const void* dw2, const void* db2,
    const void* vw1, const void* vb1, const void* vw2, const void* vb2,
    float* __restrict__ wf, const void* __restrict__ det) {
  int i = blockIdx.x * blockDim.x + threadIdx.x;
  if (i >= WFTOT) return;
  if (is_bf(det))
    prep_body((const bf16*)w1, (const bf16*)b1, (const bf16*)w2, (const bf16*)b2,
              (const bf16*)dw1, (const bf16*)db1, (const bf16*)dw2, (const bf16*)db2,
              (const bf16*)vw1, (const bf16*)vb1, (const bf16*)vw2, (const bf16*)vb2, wf, i);
  else
    prep_body((const float*)w1, (const float*)b1, (const float*)w2, (const float*)b2,
              (const float*)dw1, (const float*)db1, (const float*)dw2, (const float*)db2,
              (const float*)vw1, (const float*)vb1, (const float*)vw2, (const float*)vb2, wf, i);
}

// one wave per node; lane = feature. h = relu(LN(x@enc_w + enc_b)*g + b)
// epilogue: p0[node][j] = b1_0[j] + sum_k h_k W1_0[k][j]  (layer-0 node precompute)
__global__ __launch_bounds__(256) void encoder_kernel(
    const void* __restrict__ x, const void* __restrict__ enc_w,
    const void* __restrict__ enc_b, const void* __restrict__ g,
    const void* __restrict__ b, float* __restrict__ h,
    float* __restrict__ pout, const float* __restrict__ nw1,
    const float* __restrict__ nb1, const void* __restrict__ det) {
  int node = (blockIdx.x * blockDim.x + threadIdx.x) >> 6;
  int lane = threadIdx.x & 63;
  if (node >= NN) return;
  int jl = lane & 31, half = lane >> 5;
  float xv[INC], wv[INC], ebv, gv, bv;
  if (is_bf(det)) {
    const bf16* xp = (const bf16*)x + node * INC;
    const bf16* wp = (const bf16*)enc_w;
    #pragma unroll
    for (int k = 0; k < INC; k++) { xv[k] = b2f(xp[k]); wv[k] = b2f(wp[k * HD + lane]); }
    ebv = b2f(((const bf16*)enc_b)[lane]);
    gv  = b2f(((const bf16*)g)[lane]);
    bv  = b2f(((const bf16*)b)[lane]);
  } else {
    const float* xp = (const float*)x + node * INC;
    const float* wp = (const float*)enc_w;
    #pragma unroll
    for (int k = 0; k < INC; k++) { xv[k] = xp[k]; wv[k] = wp[k * HD + lane]; }
    ebv = ((const float*)enc_b)[lane];
    gv  = ((const float*)g)[lane];
    bv  = ((const float*)b)[lane];
  }
  float acc = ebv;
  #pragma unroll
  for (int k = 0; k < INC; k++) acc += xv[k] * wv[k];
  // one-pass LN: two independent xor-chains overlap in the DS pipe
  float s1 = acc, s2 = acc * acc;
  #pragma unroll
  for (int o = 32; o; o >>= 1) { s1 += __shfl_xor(s1, o); s2 += __shfl_xor(s2, o); }
  float mu = s1 * (1.0f / 64.0f);
  float var = fmaxf(s2 * (1.0f / 64.0f) - mu * mu, 0.0f);
  float d = acc - mu;
  float hv = fmaxf(d * rsqrtf(var + EPSV) * gv + bv, 0.0f);
  __builtin_nontemporal_store(hv, &h[node * HD + lane]);
  // p0 epilogue: halves split the k-range, combine, lanes<32 write
  float pacc = 0.0f;
  #pragma unroll
  for (int k = 0; k < 32; k++) {
    int kk = k + (half << 5);
    pacc += __shfl(hv, kk) * nw1[kk * 32 + jl];
  }
  pacc += __shfl_xor(pacc, 32);
  if (half == 0) pout[node * 32 + jl] = pacc + nb1[jl];
}

__global__ __launch_bounds__(256) void count_kernel(const int* __restrict__ ei,
                                                    int* __restrict__ cnt) {
  int e = blockIdx.x * blockDim.x + threadIdx.x;
  if (e < NE) atomicAdd(&cnt[ei[NE + e]], 1);
}

__global__ __launch_bounds__(256) void scan1_kernel(const int* __restrict__ cnt,
                                                    int* __restrict__ ex,
                                                    int* __restrict__ bsum) {
  __shared__ int s[256];
  int t = threadIdx.x, idx = blockIdx.x * 256 + t;
  int v = (idx < NN) ? cnt[idx] : 0;
  s[t] = v;
  __syncthreads();
  #pragma unroll
  for (int off = 1; off < 256; off <<= 1) {
    int u = (t >= off) ? s[t - off] : 0;
    __syncthreads();
    s[t] += u;
    __syncthreads();
  }
  if (idx < NN) ex[idx] = s[t] - v;
  if (t == 255) bsum[blockIdx.x] = s[255];
}

__global__ __launch_bounds__(256) void scan2_kernel(int* __restrict__ bsum,
                                                    int* __restrict__ boff) {
  __shared__ int s[256];
  int t = threadIdx.x;
  int v = (t < NB1) ? bsum[t] : 0;
  s[t] = v;
  __syncthreads();
  #pragma unroll
  for (int off = 1; off < 256; off <<= 1) {
    int u = (t >= off) ? s[t - off] : 0;
    __syncthreads();
    s[t] += u;
    __syncthreads();
  }
  boff[t] = s[t] - v;
}

__global__ __launch_bounds__(256) void scan3_kernel(int* __restrict__ rs,
                                                    const int* __restrict__ boff,
                                                    int* __restrict__ cursor) {
  int idx = blockIdx.x * 256 + threadIdx.x;
  if (idx >= NN) return;
  int v = rs[idx] + boff[blockIdx.x];
  rs[idx] = v;
  cursor[idx] = v;
}

__global__ __launch_bounds__(256) void scatter_kernel(
    const int* __restrict__ ei, const void* __restrict__ attr,
    int* __restrict__ cursor, float4* __restrict__ csr,
    const void* __restrict__ det) {
  int e = blockIdx.x * blockDim.x + threadIdx.x;
  if (e >= NE) return;
  int src = ei[e];
  int dst = ei[NE + e];
  float a0, a1, a2;
  if (is_bf(det)) {
    const bf16* ap = (const bf16*)attr + 3 * e;
    a0 = b2f(ap[0]); a1 = b2f(ap[1]); a2 = b2f(ap[2]);
  } else {
    const float* ap = (const float*)attr + 3 * e;
    a0 = ap[0]; a1 = ap[1]; a2 = ap[2];
  }
  int pos = atomicAdd(&cursor[dst], 1);
  float4 v; v.x = a0; v.y = a1; v.z = a2; v.w = __int_as_float(src);
  csr[pos] = v;
}

// fallback path only (ws too small for ping-pong): p = b1 + h@W1
__global__ __launch_bounds__(256) void node_pre_kernel(
    const float* __restrict__ h, const float* __restrict__ w1,
    const float* __restrict__ b1, float* __restrict__ p) {
  int t = blockIdx.x * blockDim.x + threadIdx.x;
  int node = t >> 5;
  int j = t & 31;
  if (node >= NN) return;
  const float* hr = h + node * HD;
  float acc = b1[j];
  #pragma unroll
  for (int k = 0; k < HD; k++) acc += hr[k] * w1[k * 32 + j];
  p[node * 32 + j] = acc;
}

// fused gather + hsum + node-level @W2 + mean + residual + LN
// + optional p^{l+1} epilogue (do_pnext) + heads epilogue (layer==2).
// One wave per dst node. Edge loop restructured for memory-level parallelism:
//  - lane-cooperative csr batch: ONE float4 load fetches 16 edge records
//    (lane&15 indexed), bpermute broadcasts src/attr per edge
//  - all 8 pin[src] gathers per batch issued before any consumption
//  - unified masked tail (no serial 2-at-a-time path)
//  - next batch's csr record prefetched before processing current
__global__ __launch_bounds__(256) void gather_kernel(
    float* __restrict__ h, const float* __restrict__ pin,
    float* __restrict__ pnext, const float4* __restrict__ csr,
    const int* __restrict__ rs, const int* __restrict__ cnt,
    const float* __restrict__ w1a, const float* __restrict__ w2,
    const float* __restrict__ b2v, const void* __restrict__ gbase,
    const void* __restrict__ bbase, int layer,
    const float* __restrict__ nw1, const float* __restrict__ nb1,
    int do_pnext, const float* __restrict__ wf, void* __restrict__ out,
    const void* __restrict__ det) {
  int node = (blockIdx.x * blockDim.x + threadIdx.x) >> 6;
  int lane = threadIdx.x & 63;
  if (node >= NN) return;
  int jl = lane & 31, half = lane >> 5, lidx = lane & 15;
  float wa0 = w1a[jl], wa1 = w1a[32 + jl], wa2 = w1a[64 + jl];
  int s = rs[node], c = cnt[node];
  float hres = __builtin_nontemporal_load(&h[node * HD + lane]);  // residual, issues early

  bool isbf = is_bf(det);
  int idx = layer * HD + lane;
  float gv, bv;
  if (isbf) {
    gv = b2f(((const bf16*)gbase)[idx]);
    bv = b2f(((const bf16*)bbase)[idx]);
  } else {
    gv = ((const float*)gbase)[idx];
    bv = ((const float*)bbase)[idx];
  }

  float acc = 0.0f;
  // prefetch batch 0
  float4 ed;
  if (lidx < c) ed = ldnt4(&csr[s + lidx]);
  else { ed.x = 0.f; ed.y = 0.f; ed.z = 0.f; ed.w = 0.f; }  // src=0: safe gather addr

  for (int b0 = 0; b0 < c; b0 += 16) {
    float4 cur = ed;
    // prefetch next batch (independent of current batch's chain)
    int nidx = b0 + 16 + lidx;
    if (nidx < c) ed = ldnt4(&csr[s + nidx]);
    else { ed.x = 0.f; ed.y = 0.f; ed.z = 0.f; ed.w = 0.f; }
    // broadcast all 8 srcs (half0: even edges, half1: odd edges)
    float sf[8];
    #pragma unroll
    for (int t = 0; t < 8; t++) sf[t] = __shfl(cur.w, (t << 1) | half);
    // issue all 8 gathers back-to-back -> 8 outstanding per wave
    float q[8];
    #pragma unroll
    for (int t = 0; t < 8; t++) q[t] = pin[__float_as_int(sf[t]) * 32 + jl];
    // consume as loads land; invalid edges masked via cndmask
    #pragma unroll
    for (int t = 0; t < 8; t++) {
      int eoff = (t << 1) | half;
      float a0 = __shfl(cur.x, eoff);
      float a1 = __shfl(cur.y, eoff);
      float a2 = __shfl(cur.z, eoff);
      float r = fmaxf(q[t] + a0 * wa0 + a1 * wa1 + a2 * wa2, 0.0f);
      acc += (b0 + eoff < c) ? r : 0.0f;
    }
  }
  acc += __shfl_xor(acc, 32);   // both halves now hold full hsum[jl]

  // node-level second linear layer
  float m = 0.0f;
  #pragma unroll
  for (int j = 0; j < 32; j++) m += __shfl(acc, j) * w2[j * HD + lane];
  float aggv = (c > 0) ? (m / (float)c + b2v[lane]) : 0.0f;

  // one-pass LN: sum and sumsq chains are independent -> DS latencies overlap
  float v = hres + aggv;
  float s1 = v, s2 = v * v;
  #pragma unroll
  for (int o = 32; o; o >>= 1) { s1 += __shfl_xor(s1, o); s2 += __shfl_xor(s2, o); }
  float mu = s1 * (1.0f / 64.0f);
  float var = fmaxf(s2 * (1.0f / 64.0f) - mu * mu, 0.0f);
  float d = v - mu;
  float hv = d * rsqrtf(var + EPSV) * gv + bv;

  if (do_pnext) {   // p^{l+1} epilogue (ping-pong buffer; uniform branch)
    float pacc = 0.0f;
    #pragma unroll
    for (int k = 0; k < 32; k++) {
      int kk = k + (half << 5);
      pacc += __shfl(hv, kk) * nw1[kk * 32 + jl];
    }
    pacc += __shfl_xor(pacc, 32);
    if (half == 0) pnext[node * 32 + jl] = pacc + nb1[jl];
  }

  if (layer == 2) {  // heads epilogue; h store not needed
    const float* w1h = wf + (half ? VW1F : DW1F);
    float acc2 = half ? wf[VB1F + jl] : wf[DB1F + jl];
    #pragma unroll
    for (int k = 0; k < HD; k++) acc2 += __shfl(hv, k) * w1h[k * 32 + jl];
    acc2 = fmaxf(acc2, 0.0f);
    float r0, r1;
    if (half == 0) { r0 = acc2 * wf[DW2F + jl]; r1 = 0.0f; }
    else           { r0 = acc2 * wf[VW2F + 2 * jl]; r1 = acc2 * wf[VW2F + 2 * jl + 1]; }
    #pragma unroll
    for (int o = 16; o; o >>= 1) { r0 += __shfl_xor(r0, o); r1 += __shfl_xor(r1, o); }
    if (lane == 0) {
      float d0 = r0 + wf[DB2F];
      if (isbf) ((bf16*)out)[node] = __float2bfloat16(d0);
      else      ((float*)out)[node] = d0;
    }
    if (lane == 32) {
      float v0 = r0 + wf[VB2F], v1 = r1 + wf[VB2F + 1];
      if (isbf) {
        ((bf16*)out)[NN + 2 * node]     = __float2bfloat16(v0);
        ((bf16*)out)[NN + 2 * node + 1] = __float2bfloat16(v1);
      } else {
        ((float*)out)[NN + 2 * node]     = v0;
        ((float*)out)[NN + 2 * node + 1] = v1;
      }
    }
  } else {
    __builtin_nontemporal_store(hv, &h[node * HD + lane]);
  }
}

extern "C" void kernel_launch(void* const* d_in, const int* in_sizes, int n_in,
                              void* d_out, int out_size, void* d_ws, size_t ws_size,
                              hipStream_t stream) {
  const void* x     = d_in[0];
  const int*  ei    = (const int*)d_in[1];
  const void* attr  = d_in[2];
  const void* enc_w = d_in[3];
  const void* enc_b = d_in[4];
  const void* enc_g = d_in[5];
  const void* enc_bb= d_in[6];
  const void* mw1   = d_in[7];
  const void* mb1   = d_in[8];
  const void* mw2   = d_in[9];
  const void* mb2   = d_in[10];
  const void* lng   = d_in[11];
  const void* lnb   = d_in[12];
  const void* dw1   = d_in[13];
  const void* db1   = d_in[14];
  const void* dw2   = d_in[15];
  const void* db2   = d_in[16];
  const void* vw1   = d_in[17];
  const void* vb1   = d_in[18];
  const void* vw2   = d_in[19];
  const void* vb2   = d_in[20];

  float* ws    = (float*)d_ws;
  float* h     = ws + H_OFF;
  float* p0    = ws + P0_OFF;
  float4* csr  = (float4*)(ws + CSR_OFF);
  float* wf    = ws + WF_OFF;
  int*   cnti  = (int*)(ws + CNTI_OFF);
  int*   rs    = (int*)(ws + RS_OFF);
  int*   cur   = (int*)(ws + CUR_OFF);
  int*   bsum  = (int*)(ws + BSUM_OFF);
  int*   boff  = (int*)(ws + BOFF_OFF);
  float* p1    = ws + P1_OFF;
  bool roomy = ws_size >= WS_NEED_ROOMY;  // host-side constant per session — graph-safe

  hipMemsetAsync(cnti, 0, (size_t)NN * sizeof(int), stream);
  prep_kernel<<<(WFTOT + 255) / 256, 256, 0, stream>>>(
      mw1, mb1, mw2, mb2, dw1, db1, dw2, db2, vw1, vb1, vw2, vb2, wf, enc_g);
  encoder_kernel<<<(NN + 3) / 4, 256, 0, stream>>>(
      x, enc_w, enc_b, enc_g, enc_bb, h, p0, wf + W1F, wf + B1F, enc_g);
  count_kernel<<<(NE + 255) / 256, 256, 0, stream>>>(ei, cnti);
  scan1_kernel<<<NB1, 256, 0, stream>>>(cnti, rs, bsum);
  scan2_kernel<<<1, 256, 0, stream>>>(bsum, boff);
  scan3_kernel<<<NB1, 256, 0, stream>>>(rs, boff, cur);
  scatter_kernel<<<(NE + 255) / 256, 256, 0, stream>>>(ei, attr, cur, csr, enc_g);

  for (int l = 0; l < 3; l++) {
    float* pin  = (roomy && (l & 1)) ? p1 : p0;
    float* pnxt = (roomy && !(l & 1)) ? p1 : p0;
    if (!roomy && l > 0) {
      node_pre_kernel<<<(NN * 32 + 255) / 256, 256, 0, stream>>>(
          h, wf + W1F + l * 2144, wf + B1F + l * 32, p0);
      pin = p0; pnxt = p0;
    }
    int do_pnext = (roomy && l < 2) ? 1 : 0;
    int nl = (l < 2) ? l + 1 : l;
    gather_kernel<<<(NN + 3) / 4, 256, 0, stream>>>(
        h, pin, pnxt, csr, rs, cnti,
        wf + W1F + l * 2144 + 64 * 32, wf + W2F + l * 2048, wf + B2F + l * 64,
        lng, lnb, l,
        wf + W1F + nl * 2144, wf + B1F + nl * 32, do_pnext,
        wf, d_out, enc_g);
  }
}

// Round 2
// 418.993 us; speedup vs baseline: 1.1002x; 1.1002x over previous
//
#include <hip/hip_runtime.h>
#include <hip/hip_bf16.h>

typedef __hip_bfloat16 bf16;
typedef unsigned int u32;
typedef float f4v __attribute__((ext_vector_type(4)));

#define NN 50000
#define NE 800000
#define INC 16
#define HD 64
#define EPSV 1e-5f
#define NB1 196   // ceil(NN/256)

__device__ __forceinline__ float b2f(bf16 v) { return __bfloat162float(v); }
__device__ __forceinline__ bool is_bf(const void* det) {
  return *(const u32*)det == 0x3F803F80u;  // enc_ln_g all-ones: bf16 pair vs fp32 1.0
}

__device__ __forceinline__ float4 ldnt4(const float4* p) {
  f4v t = __builtin_nontemporal_load(reinterpret_cast<const f4v*>(p));
  float4 r; r.x = t[0]; r.y = t[1]; r.z = t[2]; r.w = t[3];
  return r;
}

template<typename T> __device__ __forceinline__ float ldv(const T* p, int i);
template<> __device__ __forceinline__ float ldv<float>(const float* p, int i) { return p[i]; }
template<> __device__ __forceinline__ float ldv<bf16>(const bf16* p, int i) { return b2f(p[i]); }

// ---- fp32 weight scratch (wf) layout, element offsets ----
#define W1F   0        // mlp_w1  [3][67][32] = 6432
#define B1F   6432     // mlp_b1  [3][32]     = 96
#define W2F   6528     // mlp_w2  [3][32][64] = 6144
#define B2F   12672    // mlp_b2  [3][64]     = 192
#define DW1F  12864    // depth_w1 [64][32]   = 2048
#define DB1F  14912    // depth_b1 [32]
#define DW2F  14944    // depth_w2 [32]
#define DB2F  14976    // depth_b2 [1]
#define VW1F  14977    // vel_w1  [64][32]    = 2048
#define VB1F  17025    // vel_b1  [32]
#define VW2F  17057    // vel_w2  [32][2]     = 64
#define VB2F  17121    // vel_b2  [2]
#define WFTOT 17123

// ---- workspace layout (float element offsets) ----
#define H_OFF    0                      // [NN*64]
#define P0_OFF   3200000                // [NN*32]
#define CSR_OFF  4800000                // [NE*4] (a0,a1,a2,src)
#define WF_OFF   8000000                // [WFTOT]
#define CNTI_OFF (WF_OFF + WFTOT)       // int [NN]
#define RS_OFF   (CNTI_OFF + NN)        // int [NN]
#define CUR_OFF  (RS_OFF + NN)          // int [NN]
#define BSUM_OFF (CUR_OFF + NN)         // int [256]
#define BOFF_OFF (BSUM_OFF + 256)       // int [256]
#define P1_OFF   (BOFF_OFF + 256)       // [NN*32] optional ping-pong buffer
#define WS_NEED_ROOMY ((size_t)(P1_OFF + NN * 32) * 4)

template<typename T>
__device__ __forceinline__ void prep_body(
    const T* w1, const T* b1, const T* w2, const T* b2,
    const T* dw1, const T* db1, const T* dw2, const T* db2,
    const T* vw1, const T* vb1, const T* vw2, const T* vb2,
    float* wf, int i) {
  float v;
  if      (i < B1F)  v = ldv(w1,  i - W1F);
  else if (i < W2F)  v = ldv(b1,  i - B1F);
  else if (i < B2F)  v = ldv(w2,  i - W2F);
  else if (i < DW1F) v = ldv(b2,  i - B2F);
  else if (i < DB1F) v = ldv(dw1, i - DW1F);
  else if (i < DW2F) v = ldv(db1, i - DB1F);
  else if (i < DB2F) v = ldv(dw2, i - DW2F);
  else if (i < VW1F) v = ldv(db2, i - DB2F);
  else if (i < VB1F) v = ldv(vw1, i - VW1F);
  else if (i < VW2F) v = ldv(vb1, i - VB1F);
  else if (i < VB2F) v = ldv(vw2, i - VW2F);
  else               v = ldv(vb2, i - VB2F);
  wf[i] = v;
}

__global__ __launch_bounds__(256) void prep_kernel(
    const void* w1, const void* b1, const void* w2, const void* b2,
    const void* dw1, const void* db1, const void* dw2, const void* db2,
    const void* vw1, const void* vb1, const void* vw2, const void* vb2,
    float* __restrict__ wf, const void* __restrict__ det) {
  int i = blockIdx.x * blockDim.x + threadIdx.x;
  if (i >= WFTOT) return;
  if (is_bf(det))
    prep_body((const bf16*)w1, (const bf16*)b1, (const bf16*)w2, (const bf16*)b2,
              (const bf16*)dw1, (const bf16*)db1, (const bf16*)dw2, (const bf16*)db2,
              (const bf16*)vw1, (const bf16*)vb1, (const bf16*)vw2, (const bf16*)vb2, wf, i);
  else
    prep_body((const float*)w1, (const float*)b1, (const float*)w2, (const float*)b2,
              (const float*)dw1, (const float*)db1, (const float*)dw2, (const float*)db2,
              (const float*)vw1, (const float*)vb1, (const float*)vw2, (const float*)vb2, wf, i);
}

// one wave per node; lane = feature. h = relu(LN(x@enc_w + enc_b)*g + b)
// epilogue: p0[node][j] = b1_0[j] + sum_k h_k W1_0[k][j]  (layer-0 node precompute)
// hv broadcast via LDS b128 reads instead of 32 shuffles.
__global__ __launch_bounds__(256) void encoder_kernel(
    const void* __restrict__ x, const void* __restrict__ enc_w,
    const void* __restrict__ enc_b, const void* __restrict__ g,
    const void* __restrict__ b, float* __restrict__ h,
    float* __restrict__ pout, const float* __restrict__ nw1,
    const float* __restrict__ nb1, const void* __restrict__ det) {
  __shared__ float shv[4][64];
  int node = (blockIdx.x * blockDim.x + threadIdx.x) >> 6;
  int lane = threadIdx.x & 63;
  int w = threadIdx.x >> 6;
  if (node >= NN) return;
  int jl = lane & 31, half = lane >> 5;
  float xv[INC], wv[INC], ebv, gv, bv;
  if (is_bf(det)) {
    const bf16* xp = (const bf16*)x + node * INC;
    const bf16* wp = (const bf16*)enc_w;
    #pragma unroll
    for (int k = 0; k < INC; k++) { xv[k] = b2f(xp[k]); wv[k] = b2f(wp[k * HD + lane]); }
    ebv = b2f(((const bf16*)enc_b)[lane]);
    gv  = b2f(((const bf16*)g)[lane]);
    bv  = b2f(((const bf16*)b)[lane]);
  } else {
    const float* xp = (const float*)x + node * INC;
    const float* wp = (const float*)enc_w;
    #pragma unroll
    for (int k = 0; k < INC; k++) { xv[k] = xp[k]; wv[k] = wp[k * HD + lane]; }
    ebv = ((const float*)enc_b)[lane];
    gv  = ((const float*)g)[lane];
    bv  = ((const float*)b)[lane];
  }
  float acc = ebv;
  #pragma unroll
  for (int k = 0; k < INC; k++) acc += xv[k] * wv[k];
  // one-pass LN: two independent xor-chains overlap
  float s1 = acc, s2 = acc * acc;
  #pragma unroll
  for (int o = 32; o; o >>= 1) { s1 += __shfl_xor(s1, o); s2 += __shfl_xor(s2, o); }
  float mu = s1 * (1.0f / 64.0f);
  float var = fmaxf(s2 * (1.0f / 64.0f) - mu * mu, 0.0f);
  float d = acc - mu;
  float hv = fmaxf(d * rsqrtf(var + EPSV) * gv + bv, 0.0f);
  __builtin_nontemporal_store(hv, &h[node * HD + lane]);
  // p0 epilogue: halves split the k-range; hv broadcast via LDS (same wave, no barrier)
  shv[w][lane] = hv;
  float pacc = 0.0f;
  int kb = half << 5;
  #pragma unroll
  for (int k4 = 0; k4 < 32; k4 += 4) {
    float4 h4 = *reinterpret_cast<const float4*>(&shv[w][kb + k4]);
    int kk = kb + k4;
    pacc += h4.x * nw1[kk * 32 + jl] + h4.y * nw1[(kk + 1) * 32 + jl]
          + h4.z * nw1[(kk + 2) * 32 + jl] + h4.w * nw1[(kk + 3) * 32 + jl];
  }
  pacc += __shfl_xor(pacc, 32);
  if (half == 0) pout[node * 32 + jl] = pacc + nb1[jl];
}

__global__ __launch_bounds__(256) void count_kernel(const int* __restrict__ ei,
                                                    int* __restrict__ cnt) {
  int e = blockIdx.x * blockDim.x + threadIdx.x;
  if (e < NE) atomicAdd(&cnt[ei[NE + e]], 1);
}

__global__ __launch_bounds__(256) void scan1_kernel(const int* __restrict__ cnt,
                                                    int* __restrict__ ex,
                                                    int* __restrict__ bsum) {
  __shared__ int s[256];
  int t = threadIdx.x, idx = blockIdx.x * 256 + t;
  int v = (idx < NN) ? cnt[idx] : 0;
  s[t] = v;
  __syncthreads();
  #pragma unroll
  for (int off = 1; off < 256; off <<= 1) {
    int u = (t >= off) ? s[t - off] : 0;
    __syncthreads();
    s[t] += u;
    __syncthreads();
  }
  if (idx < NN) ex[idx] = s[t] - v;
  if (t == 255) bsum[blockIdx.x] = s[255];
}

__global__ __launch_bounds__(256) void scan2_kernel(int* __restrict__ bsum,
                                                    int* __restrict__ boff) {
  __shared__ int s[256];
  int t = threadIdx.x;
  int v = (t < NB1) ? bsum[t] : 0;
  s[t] = v;
  __syncthreads();
  #pragma unroll
  for (int off = 1; off < 256; off <<= 1) {
    int u = (t >= off) ? s[t - off] : 0;
    __syncthreads();
    s[t] += u;
    __syncthreads();
  }
  boff[t] = s[t] - v;
}

__global__ __launch_bounds__(256) void scan3_kernel(int* __restrict__ rs,
                                                    const int* __restrict__ boff,
                                                    int* __restrict__ cursor) {
  int idx = blockIdx.x * 256 + threadIdx.x;
  if (idx >= NN) return;
  int v = rs[idx] + boff[blockIdx.x];
  rs[idx] = v;
  cursor[idx] = v;
}

__global__ __launch_bounds__(256) void scatter_kernel(
    const int* __restrict__ ei, const void* __restrict__ attr,
    int* __restrict__ cursor, float4* __restrict__ csr,
    const void* __restrict__ det) {
  int e = blockIdx.x * blockDim.x + threadIdx.x;
  if (e >= NE) return;
  int src = ei[e];
  int dst = ei[NE + e];
  float a0, a1, a2;
  if (is_bf(det)) {
    const bf16* ap = (const bf16*)attr + 3 * e;
    a0 = b2f(ap[0]); a1 = b2f(ap[1]); a2 = b2f(ap[2]);
  } else {
    const float* ap = (const float*)attr + 3 * e;
    a0 = ap[0]; a1 = ap[1]; a2 = ap[2];
  }
  int pos = atomicAdd(&cursor[dst], 1);
  float4 v; v.x = a0; v.y = a1; v.z = a2; v.w = __int_as_float(src);
  csr[pos] = v;
}

// fallback path only (ws too small for ping-pong): p = b1 + h@W1
__global__ __launch_bounds__(256) void node_pre_kernel(
    const float* __restrict__ h, const float* __restrict__ w1,
    const float* __restrict__ b1, float* __restrict__ p) {
  int t = blockIdx.x * blockDim.x + threadIdx.x;
  int node = t >> 5;
  int j = t & 31;
  if (node >= NN) return;
  const float* hr = h + node * HD;
  float acc = b1[j];
  #pragma unroll
  for (int k = 0; k < HD; k++) acc += hr[k] * w1[k * 32 + j];
  p[node * 32 + j] = acc;
}

// fused gather + hsum + node-level @W2 + mean + residual + LN
// + optional p^{l+1} epilogue (do_pnext) + heads epilogue (layer==2).
// One wave per dst node; 128-thread blocks (2 nodes) to limit WG-slot
// fragmentation from degree variance.
// Edge loop: 16 edges/step, 8 broadcast csr loads then 8 gathers issued
// back-to-back (max MLP, no shuffles in chain), next-step csr prefetch,
// masked tail via clamped index (no serial tail loop).
// Epilogues: acc/hv broadcast through LDS ds_read_b128 instead of shfl loops.
__global__ __launch_bounds__(128) void gather_kernel(
    float* __restrict__ h, const float* __restrict__ pin,
    float* __restrict__ pnext, const float4* __restrict__ csr,
    const int* __restrict__ rs, const int* __restrict__ cnt,
    const float* __restrict__ w1a, const float* __restrict__ w2,
    const float* __restrict__ b2v, const void* __restrict__ gbase,
    const void* __restrict__ bbase, int layer,
    const float* __restrict__ nw1, const float* __restrict__ nb1,
    int do_pnext, const float* __restrict__ wf, void* __restrict__ out,
    const void* __restrict__ det) {
  __shared__ float sacc[2][32];
  __shared__ float shv[2][64];
  int node = (blockIdx.x * blockDim.x + threadIdx.x) >> 6;
  int lane = threadIdx.x & 63;
  int w = threadIdx.x >> 6;
  if (node >= NN) return;
  int jl = lane & 31, half = lane >> 5;
  float wa0 = w1a[jl], wa1 = w1a[32 + jl], wa2 = w1a[64 + jl];
  int s = rs[node], c = cnt[node];
  float hres = __builtin_nontemporal_load(&h[node * HD + lane]);  // residual, issues early

  bool isbf = is_bf(det);
  int idx = layer * HD + lane;
  float gv, bv;
  if (isbf) {
    gv = b2f(((const bf16*)gbase)[idx]);
    bv = b2f(((const bf16*)bbase)[idx]);
  } else {
    gv = ((const float*)gbase)[idx];
    bv = ((const float*)bbase)[idx];
  }

  float acc = 0.0f;
  if (c > 0) {
    int cm1 = c - 1;
    float4 ed[8];
    #pragma unroll
    for (int t = 0; t < 8; t++) {
      int k = min(2 * t + half, cm1);
      ed[t] = ldnt4(&csr[s + k]);
    }
    for (int b0 = 0; b0 < c; b0 += 16) {
      // 1) issue all 8 gathers (2 edges per instruction, halves differ)
      float q[8];
      #pragma unroll
      for (int t = 0; t < 8; t++) q[t] = pin[__float_as_int(ed[t].w) * 32 + jl];
      // 2) attr dot-products from current records (no wait on q)
      float pa[8];
      #pragma unroll
      for (int t = 0; t < 8; t++)
        pa[t] = ed[t].x * wa0 + ed[t].y * wa1 + ed[t].z * wa2;
      // 3) prefetch next 16 records (wave-uniform branch)
      int nb = b0 + 16;
      if (nb < c) {
        #pragma unroll
        for (int t = 0; t < 8; t++) {
          int k = min(nb + 2 * t + half, cm1);
          ed[t] = ldnt4(&csr[s + k]);
        }
      }
      // 4) consume gathers, masked accumulate
      #pragma unroll
      for (int t = 0; t < 8; t++) {
        float r = fmaxf(q[t] + pa[t], 0.0f);
        acc += ((b0 + 2 * t + half) < c) ? r : 0.0f;
      }
    }
  }
  acc += __shfl_xor(acc, 32);   // both halves now hold full hsum[jl]

  // node-level second linear layer: acc broadcast via LDS b128 reads
  if (half == 0) sacc[w][jl] = acc;
  float m = 0.0f;
  #pragma unroll
  for (int j4 = 0; j4 < 32; j4 += 4) {
    float4 a4 = *reinterpret_cast<const float4*>(&sacc[w][j4]);
    m += a4.x * w2[(j4 + 0) * HD + lane] + a4.y * w2[(j4 + 1) * HD + lane]
       + a4.z * w2[(j4 + 2) * HD + lane] + a4.w * w2[(j4 + 3) * HD + lane];
  }
  float aggv = (c > 0) ? (m / (float)c + b2v[lane]) : 0.0f;

  // one-pass LN
  float v = hres + aggv;
  float s1 = v, s2 = v * v;
  #pragma unroll
  for (int o = 32; o; o >>= 1) { s1 += __shfl_xor(s1, o); s2 += __shfl_xor(s2, o); }
  float mu = s1 * (1.0f / 64.0f);
  float var = fmaxf(s2 * (1.0f / 64.0f) - mu * mu, 0.0f);
  float d = v - mu;
  float hv = d * rsqrtf(var + EPSV) * gv + bv;

  shv[w][lane] = hv;   // broadcast buffer for epilogues (same wave, no barrier)

  if (do_pnext) {   // p^{l+1} epilogue (ping-pong buffer; uniform branch)
    float pacc = 0.0f;
    int kb = half << 5;
    #pragma unroll
    for (int k4 = 0; k4 < 32; k4 += 4) {
      float4 h4 = *reinterpret_cast<const float4*>(&shv[w][kb + k4]);
      int kk = kb + k4;
      pacc += h4.x * nw1[kk * 32 + jl] + h4.y * nw1[(kk + 1) * 32 + jl]
            + h4.z * nw1[(kk + 2) * 32 + jl] + h4.w * nw1[(kk + 3) * 32 + jl];
    }
    pacc += __shfl_xor(pacc, 32);
    if (half == 0) pnext[node * 32 + jl] = pacc + nb1[jl];
  }

  if (layer == 2) {  // heads epilogue; h store not needed
    const float* w1h = wf + (half ? VW1F : DW1F);
    float acc2 = half ? wf[VB1F + jl] : wf[DB1F + jl];
    #pragma unroll
    for (int k4 = 0; k4 < 64; k4 += 4) {
      float4 h4 = *reinterpret_cast<const float4*>(&shv[w][k4]);
      acc2 += h4.x * w1h[(k4 + 0) * 32 + jl] + h4.y * w1h[(k4 + 1) * 32 + jl]
            + h4.z * w1h[(k4 + 2) * 32 + jl] + h4.w * w1h[(k4 + 3) * 32 + jl];
    }
    acc2 = fmaxf(acc2, 0.0f);
    float r0, r1;
    if (half == 0) { r0 = acc2 * wf[DW2F + jl]; r1 = 0.0f; }
    else           { r0 = acc2 * wf[VW2F + 2 * jl]; r1 = acc2 * wf[VW2F + 2 * jl + 1]; }
    #pragma unroll
    for (int o = 16; o; o >>= 1) { r0 += __shfl_xor(r0, o); r1 += __shfl_xor(r1, o); }
    if (lane == 0) {
      float d0 = r0 + wf[DB2F];
      if (isbf) ((bf16*)out)[node] = __float2bfloat16(d0);
      else      ((float*)out)[node] = d0;
    }
    if (lane == 32) {
      float v0 = r0 + wf[VB2F], v1 = r1 + wf[VB2F + 1];
      if (isbf) {
        ((bf16*)out)[NN + 2 * node]     = __float2bfloat16(v0);
        ((bf16*)out)[NN + 2 * node + 1] = __float2bfloat16(v1);
      } else {
        ((float*)out)[NN + 2 * node]     = v0;
        ((float*)out)[NN + 2 * node + 1] = v1;
      }
    }
  } else {
    __builtin_nontemporal_store(hv, &h[node * HD + lane]);
  }
}

extern "C" void kernel_launch(void* const* d_in, const int* in_sizes, int n_in,
                              void* d_out, int out_size, void* d_ws, size_t ws_size,
                              hipStream_t stream) {
  const void* x     = d_in[0];
  const int*  ei    = (const int*)d_in[1];
  const void* attr  = d_in[2];
  const void* enc_w = d_in[3];
  const void* enc_b = d_in[4];
  const void* enc_g = d_in[5];
  const void* enc_bb= d_in[6];
  const void* mw1   = d_in[7];
  const void* mb1   = d_in[8];
  const void* mw2   = d_in[9];
  const void* mb2   = d_in[10];
  const void* lng   = d_in[11];
  const void* lnb   = d_in[12];
  const void* dw1   = d_in[13];
  const void* db1   = d_in[14];
  const void* dw2   = d_in[15];
  const void* db2   = d_in[16];
  const void* vw1   = d_in[17];
  const void* vb1   = d_in[18];
  const void* vw2   = d_in[19];
  const void* vb2   = d_in[20];

  float* ws    = (float*)d_ws;
  float* h     = ws + H_OFF;
  float* p0    = ws + P0_OFF;
  float4* csr  = (float4*)(ws + CSR_OFF);
  float* wf    = ws + WF_OFF;
  int*   cnti  = (int*)(ws + CNTI_OFF);
  int*   rs    = (int*)(ws + RS_OFF);
  int*   cur   = (int*)(ws + CUR_OFF);
  int*   bsum  = (int*)(ws + BSUM_OFF);
  int*   boff  = (int*)(ws + BOFF_OFF);
  float* p1    = ws + P1_OFF;
  bool roomy = ws_size >= WS_NEED_ROOMY;  // host-side constant per session — graph-safe

  hipMemsetAsync(cnti, 0, (size_t)NN * sizeof(int), stream);
  prep_kernel<<<(WFTOT + 255) / 256, 256, 0, stream>>>(
      mw1, mb1, mw2, mb2, dw1, db1, dw2, db2, vw1, vb1, vw2, vb2, wf, enc_g);
  encoder_kernel<<<(NN + 3) / 4, 256, 0, stream>>>(
      x, enc_w, enc_b, enc_g, enc_bb, h, p0, wf + W1F, wf + B1F, enc_g);
  count_kernel<<<(NE + 255) / 256, 256, 0, stream>>>(ei, cnti);
  scan1_kernel<<<NB1, 256, 0, stream>>>(cnti, rs, bsum);
  scan2_kernel<<<1, 256, 0, stream>>>(bsum, boff);
  scan3_kernel<<<NB1, 256, 0, stream>>>(rs, boff, cur);
  scatter_kernel<<<(NE + 255) / 256, 256, 0, stream>>>(ei, attr, cur, csr, enc_g);

  for (int l = 0; l < 3; l++) {
    float* pin  = (roomy && (l & 1)) ? p1 : p0;
    float* pnxt = (roomy && !(l & 1)) ? p1 : p0;
    if (!roomy && l > 0) {
      node_pre_kernel<<<(NN * 32 + 255) / 256, 256, 0, stream>>>(
          h, wf + W1F + l * 2144, wf + B1F + l * 32, p0);
      pin = p0; pnxt = p0;
    }
    int do_pnext = (roomy && l < 2) ? 1 : 0;
    int nl = (l < 2) ? l + 1 : l;
    gather_kernel<<<(NN + 1) / 2, 128, 0, stream>>>(
        h, pin, pnxt, csr, rs, cnti,
        wf + W1F + l * 2144 + 64 * 32, wf + W2F + l * 2048, wf + B2F + l * 64,
        lng, lnb, l,
        wf + W1F + nl * 2144, wf + B1F + nl * 32, do_pnext,
        wf, d_out, enc_g);
  }
}